// Round 1
// baseline (12581.819 us; speedup 1.0000x reference)
//
#include <hip/hip_runtime.h>
#include <math.h>

#define SEQ 2048
#define HDIM 2048
#define NHQ 16
#define NHKV 4
#define DH 128
#define NE 16
#define NI 768
#define EPSV 1e-6f

// ---------------- generic tiled fp32 GEMM: C = A(MxK) @ B(KxN) (+ R) ----------------
// dims must be multiples of 64 (true for all uses here). block = 256 threads.
__global__ void gemm64(const float* __restrict__ A, const float* __restrict__ B,
                       float* __restrict__ C, const float* __restrict__ R,
                       int M, int N, int K) {
    __shared__ float As[64][17];
    __shared__ float Bs[16][65];
    const int tid = threadIdx.x;
    const int ty = tid >> 4, tx = tid & 15;
    const int rowBase = blockIdx.y * 64;
    const int colBase = blockIdx.x * 64;
    float acc[4][4] = {};
    for (int k0 = 0; k0 < K; k0 += 16) {
        #pragma unroll
        for (int l = 0; l < 4; l++) {
            int e = tid + l * 256;
            int r = e >> 4, c = e & 15;
            As[r][c] = A[(size_t)(rowBase + r) * K + k0 + c];
        }
        #pragma unroll
        for (int l = 0; l < 4; l++) {
            int e = tid + l * 256;
            int r = e >> 6, c = e & 63;
            Bs[r][c] = B[(size_t)(k0 + r) * N + colBase + c];
        }
        __syncthreads();
        #pragma unroll
        for (int kk = 0; kk < 16; kk++) {
            float a[4], b[4];
            #pragma unroll
            for (int i = 0; i < 4; i++) a[i] = As[ty * 4 + i][kk];
            #pragma unroll
            for (int j = 0; j < 4; j++) b[j] = Bs[kk][tx * 4 + j];
            #pragma unroll
            for (int i = 0; i < 4; i++)
                #pragma unroll
                for (int j = 0; j < 4; j++)
                    acc[i][j] += a[i] * b[j];
        }
        __syncthreads();
    }
    #pragma unroll
    for (int i = 0; i < 4; i++) {
        int r = rowBase + ty * 4 + i;
        #pragma unroll
        for (int j = 0; j < 4; j++) {
            int c = colBase + tx * 4 + j;
            float v = acc[i][j];
            if (R) v += R[(size_t)r * N + c];
            C[(size_t)r * N + c] = v;
        }
    }
}

// ---------------- per-(seq,head) RMSNorm + RoPE, in place ----------------
// grid: (SEQ, NHQ+NHKV), block: 128
__global__ void norm_rope(float* __restrict__ q, float* __restrict__ k,
                          const float* __restrict__ q_scale, const float* __restrict__ k_scale) {
    const int s = blockIdx.x;
    const int h = blockIdx.y;
    const int t = threadIdx.x;
    float* ptr;
    const float* scale;
    if (h < NHQ) { ptr = q + ((size_t)s * NHQ + h) * DH; scale = q_scale; }
    else         { ptr = k + ((size_t)s * NHKV + (h - NHQ)) * DH; scale = k_scale; }
    __shared__ float sh[DH];
    __shared__ float red[128];
    float x = ptr[t];
    red[t] = x * x;
    __syncthreads();
    #pragma unroll
    for (int off = 64; off > 0; off >>= 1) {
        if (t < off) red[t] += red[t + off];
        __syncthreads();
    }
    float var = red[0] * (1.0f / DH);
    float r = rsqrtf(var + EPSV);
    float xn = x * r * scale[t];
    sh[t] = xn;
    __syncthreads();
    int i = t & 63;
    // inv_freq = 10000^(-i/64) = exp2(-i * log2(10000)/64)
    float inv_freq = exp2f(-(float)i * 0.20762050593046014f);
    float ang = (float)s * inv_freq;
    float c = cosf(ang), sn = sinf(ang);
    float y;
    if (t < 64) y = xn * c - sh[t + 64] * sn;
    else        y = xn * c + sh[t - 64] * sn;
    ptr[t] = y;
}

// ---------------- causal GQA attention, one block per (q-row, q-head) ----------------
// grid: (SEQ, NHQ), block: 128
__global__ void attn(const float* __restrict__ q, const float* __restrict__ k,
                     const float* __restrict__ v, float* __restrict__ out) {
    const int qrow = blockIdx.x;
    const int h = blockIdx.y;
    const int kvh = h >> 2;  // HQ/HKV = 4
    const int t = threadIdx.x;
    __shared__ float sq[DH];
    __shared__ float sc[SEQ];
    __shared__ float red[128];
    sq[t] = q[((size_t)qrow * NHQ + h) * DH + t];
    __syncthreads();
    const int nk = qrow + 1;
    const float scale = 0.08838834764831845f;  // 1/sqrt(128)
    for (int j = t; j < nk; j += 128) {
        const float* kr = k + ((size_t)j * NHKV + kvh) * DH;
        float d = 0.f;
        #pragma unroll
        for (int x = 0; x < DH; x += 4) {
            float4 k4 = *(const float4*)(kr + x);
            d += sq[x] * k4.x + sq[x + 1] * k4.y + sq[x + 2] * k4.z + sq[x + 3] * k4.w;
        }
        sc[j] = d * scale;
    }
    __syncthreads();
    float m = -1e30f;
    for (int j = t; j < nk; j += 128) m = fmaxf(m, sc[j]);
    red[t] = m;
    __syncthreads();
    #pragma unroll
    for (int off = 64; off > 0; off >>= 1) {
        if (t < off) red[t] = fmaxf(red[t], red[t + off]);
        __syncthreads();
    }
    m = red[0];
    __syncthreads();
    float ssum = 0.f;
    for (int j = t; j < nk; j += 128) {
        float p = __expf(sc[j] - m);
        sc[j] = p;
        ssum += p;
    }
    red[t] = ssum;
    __syncthreads();
    #pragma unroll
    for (int off = 64; off > 0; off >>= 1) {
        if (t < off) red[t] += red[t + off];
        __syncthreads();
    }
    const float inv = 1.0f / red[0];
    float acc = 0.f;
    #pragma unroll 4
    for (int j = 0; j < nk; j++)
        acc += sc[j] * v[((size_t)j * NHKV + kvh) * DH + t];
    out[((size_t)qrow * NHQ + h) * DH + t] = acc * inv;
}

// ---------------- router logits + top-2 selection ----------------
// grid: (SEQ), block: 256
__global__ void router_topk(const float* __restrict__ hbuf, const float* __restrict__ rw,
                            float* __restrict__ logits_out, int* __restrict__ sel) {
    const int tok = blockIdx.x;
    const int tid = threadIdx.x;
    __shared__ float part[256];
    const int e = tid & 15, chunk = tid >> 4;  // 16 chunks of 128
    const float* hr = hbuf + (size_t)tok * HDIM;
    float sum = 0.f;
    const int k0 = chunk * 128;
    for (int x = k0; x < k0 + 128; x++) sum += hr[x] * rw[(size_t)x * NE + e];
    part[tid] = sum;
    __syncthreads();
    if (tid < 16) {
        float s = 0.f;
        #pragma unroll
        for (int c = 0; c < 16; c++) s += part[c * 16 + tid];
        part[tid] = s;
    }
    __syncthreads();
    if (tid == 0) {
        float best = -1e30f; int bi = 0;
        for (int e2 = 0; e2 < 16; e2++) if (part[e2] > best) { best = part[e2]; bi = e2; }
        float best2 = -1e30f; int bi2 = 0;
        for (int e2 = 0; e2 < 16; e2++) if (e2 != bi && part[e2] > best2) { best2 = part[e2]; bi2 = e2; }
        sel[tok * 2]     = bi;
        sel[tok * 2 + 1] = bi2;
    }
    if (tid < 16) logits_out[(size_t)tok * NE + tid] = part[tid];
}

// ---------------- per-token 2-expert MLP + residual ----------------
// grid: (SEQ), block: 256.   out[t] = h[t] + sum_{e in top2} down_e(silu(up_e(h[t])))
__global__ void moe(const float* __restrict__ hbuf, const int* __restrict__ sel,
                    const float* __restrict__ w_up, const float* __restrict__ b_up,
                    const float* __restrict__ w_down, const float* __restrict__ b_down,
                    float* __restrict__ out) {
    const int tok = blockIdx.x;
    const int tid = threadIdx.x;
    __shared__ float sh[HDIM];  // 8 KB
    __shared__ float su[NI];    // 3 KB
    const float* hr = hbuf + (size_t)tok * HDIM;
    for (int x = tid; x < HDIM; x += 256) sh[x] = hr[x];
    float acc[8] = {};
    __syncthreads();
    for (int ei = 0; ei < 2; ei++) {
        const int ex = sel[tok * 2 + ei];
        const float* wu = w_up + (size_t)ex * HDIM * NI;
        float u0 = 0.f, u1 = 0.f, u2 = 0.f;
        for (int kk = 0; kk < HDIM; kk++) {
            const float hv = sh[kk];
            const float* wr = wu + (size_t)kk * NI;
            u0 += hv * wr[tid];
            u1 += hv * wr[tid + 256];
            u2 += hv * wr[tid + 512];
        }
        {
            float x0 = u0 + b_up[(size_t)ex * NI + tid];
            float x1 = u1 + b_up[(size_t)ex * NI + tid + 256];
            float x2 = u2 + b_up[(size_t)ex * NI + tid + 512];
            su[tid]       = x0 / (1.0f + __expf(-x0));
            su[tid + 256] = x1 / (1.0f + __expf(-x1));
            su[tid + 512] = x2 / (1.0f + __expf(-x2));
        }
        __syncthreads();
        const float* wd = w_down + (size_t)ex * NI * HDIM;
        for (int kk = 0; kk < NI; kk++) {
            const float uv = su[kk];
            const float* wr = wd + (size_t)kk * HDIM;
            #pragma unroll
            for (int l = 0; l < 8; l++) acc[l] += uv * wr[tid + l * 256];
        }
        #pragma unroll
        for (int l = 0; l < 8; l++) acc[l] += b_down[(size_t)ex * HDIM + tid + l * 256];
        __syncthreads();  // su reused by next expert
    }
    #pragma unroll
    for (int l = 0; l < 8; l++) {
        int x = tid + l * 256;
        out[(size_t)tok * HDIM + x] = sh[x] + acc[l];
    }
}

extern "C" void kernel_launch(void* const* d_in, const int* in_sizes, int n_in,
                              void* d_out, int out_size, void* d_ws, size_t ws_size,
                              hipStream_t stream) {
    (void)in_sizes; (void)n_in; (void)out_size; (void)ws_size;
    const float* hidden   = (const float*)d_in[0];
    const float* wq       = (const float*)d_in[1];
    const float* wk       = (const float*)d_in[2];
    const float* wv       = (const float*)d_in[3];
    const float* wo       = (const float*)d_in[4];
    const float* q_scale  = (const float*)d_in[5];
    const float* k_scale  = (const float*)d_in[6];
    const float* router_w = (const float*)d_in[7];
    const float* w_up     = (const float*)d_in[8];
    const float* b_up     = (const float*)d_in[9];
    const float* w_down   = (const float*)d_in[10];
    const float* b_down   = (const float*)d_in[11];

    float* out = (float*)d_out;
    float* h_out      = out;                 // (SEQ, HDIM)
    float* logits_out = out + (size_t)SEQ * HDIM;  // (SEQ, NE)

    float* q_ws    = (float*)d_ws;                       // SEQ*HDIM
    float* k_ws    = q_ws + (size_t)SEQ * HDIM;          // SEQ*NHKV*DH
    float* v_ws    = k_ws + (size_t)SEQ * NHKV * DH;     // SEQ*NHKV*DH
    float* attn_ws = v_ws + (size_t)SEQ * NHKV * DH;     // SEQ*HDIM
    int*   sel_ws  = (int*)(attn_ws + (size_t)SEQ * HDIM);

    // QKV projections
    gemm64<<<dim3(HDIM / 64, SEQ / 64), 256, 0, stream>>>(hidden, wq, q_ws, nullptr, SEQ, HDIM, HDIM);
    gemm64<<<dim3((NHKV * DH) / 64, SEQ / 64), 256, 0, stream>>>(hidden, wk, k_ws, nullptr, SEQ, NHKV * DH, HDIM);
    gemm64<<<dim3((NHKV * DH) / 64, SEQ / 64), 256, 0, stream>>>(hidden, wv, v_ws, nullptr, SEQ, NHKV * DH, HDIM);

    // q/k RMSNorm + RoPE (in place)
    norm_rope<<<dim3(SEQ, NHQ + NHKV), 128, 0, stream>>>(q_ws, k_ws, q_scale, k_scale);

    // causal GQA attention
    attn<<<dim3(SEQ, NHQ), 128, 0, stream>>>(q_ws, k_ws, v_ws, attn_ws);

    // out-proj + residual -> h (stored in d_out)
    gemm64<<<dim3(HDIM / 64, SEQ / 64), 256, 0, stream>>>(attn_ws, wo, h_out, hidden, SEQ, HDIM, HDIM);

    // router logits + top-2
    router_topk<<<dim3(SEQ), 256, 0, stream>>>(h_out, router_w, logits_out, sel_ws);

    // MoE (reads h from d_out, writes final h+moe into d_out in place, per-token)
    moe<<<dim3(SEQ), 256, 0, stream>>>(h_out, sel_ws, w_up, b_up, w_down, b_down, h_out);
}

// Round 2
// 7354.427 us; speedup vs baseline: 1.7108x; 1.7108x over previous
//
#include <hip/hip_runtime.h>
#include <math.h>

#define SEQ 2048
#define HDIM 2048
#define NHQ 16
#define NHKV 4
#define DH 128
#define NE 16
#define NI 768
#define EPSV 1e-6f
#define MAX_TILES 80

// ---------------- generic tiled fp32 GEMM: C = A(MxK) @ B(KxN) (+ R) ----------------
__global__ void gemm64(const float* __restrict__ A, const float* __restrict__ B,
                       float* __restrict__ C, const float* __restrict__ R,
                       int M, int N, int K) {
    __shared__ float As[64][17];
    __shared__ float Bs[16][65];
    const int tid = threadIdx.x;
    const int ty = tid >> 4, tx = tid & 15;
    const int rowBase = blockIdx.y * 64;
    const int colBase = blockIdx.x * 64;
    float acc[4][4] = {};
    for (int k0 = 0; k0 < K; k0 += 16) {
        #pragma unroll
        for (int l = 0; l < 4; l++) {
            int e = tid + l * 256;
            int r = e >> 4, c = e & 15;
            As[r][c] = A[(size_t)(rowBase + r) * K + k0 + c];
        }
        #pragma unroll
        for (int l = 0; l < 4; l++) {
            int e = tid + l * 256;
            int r = e >> 6, c = e & 63;
            Bs[r][c] = B[(size_t)(k0 + r) * N + colBase + c];
        }
        __syncthreads();
        #pragma unroll
        for (int kk = 0; kk < 16; kk++) {
            float a[4], b[4];
            #pragma unroll
            for (int i = 0; i < 4; i++) a[i] = As[ty * 4 + i][kk];
            #pragma unroll
            for (int j = 0; j < 4; j++) b[j] = Bs[kk][tx * 4 + j];
            #pragma unroll
            for (int i = 0; i < 4; i++)
                #pragma unroll
                for (int j = 0; j < 4; j++)
                    acc[i][j] += a[i] * b[j];
        }
        __syncthreads();
    }
    #pragma unroll
    for (int i = 0; i < 4; i++) {
        int r = rowBase + ty * 4 + i;
        #pragma unroll
        for (int j = 0; j < 4; j++) {
            int c = colBase + tx * 4 + j;
            float v = acc[i][j];
            if (R) v += R[(size_t)r * N + c];
            C[(size_t)r * N + c] = v;
        }
    }
}

// ---------------- per-(seq,head) RMSNorm + RoPE, in place ----------------
__global__ void norm_rope(float* __restrict__ q, float* __restrict__ k,
                          const float* __restrict__ q_scale, const float* __restrict__ k_scale) {
    const int s = blockIdx.x;
    const int h = blockIdx.y;
    const int t = threadIdx.x;
    float* ptr;
    const float* scale;
    if (h < NHQ) { ptr = q + ((size_t)s * NHQ + h) * DH; scale = q_scale; }
    else         { ptr = k + ((size_t)s * NHKV + (h - NHQ)) * DH; scale = k_scale; }
    __shared__ float sh[DH];
    __shared__ float red[128];
    float x = ptr[t];
    red[t] = x * x;
    __syncthreads();
    #pragma unroll
    for (int off = 64; off > 0; off >>= 1) {
        if (t < off) red[t] += red[t + off];
        __syncthreads();
    }
    float var = red[0] * (1.0f / DH);
    float r = rsqrtf(var + EPSV);
    float xn = x * r * scale[t];
    sh[t] = xn;
    __syncthreads();
    int i = t & 63;
    float inv_freq = exp2f(-(float)i * 0.20762050593046014f);
    float ang = (float)s * inv_freq;
    float c = cosf(ang), sn = sinf(ang);
    float y;
    if (t < 64) y = xn * c - sh[t + 64] * sn;
    else        y = xn * c + sh[t - 64] * sn;
    ptr[t] = y;
}

// ---------------- causal GQA attention, one block per (q-row, q-head) ----------------
__global__ void attn(const float* __restrict__ q, const float* __restrict__ k,
                     const float* __restrict__ v, float* __restrict__ out) {
    const int qrow = blockIdx.x;
    const int h = blockIdx.y;
    const int kvh = h >> 2;
    const int t = threadIdx.x;
    __shared__ float sq[DH];
    __shared__ float sc[SEQ];
    __shared__ float red[128];
    sq[t] = q[((size_t)qrow * NHQ + h) * DH + t];
    __syncthreads();
    const int nk = qrow + 1;
    const float scale = 0.08838834764831845f;
    for (int j = t; j < nk; j += 128) {
        const float* kr = k + ((size_t)j * NHKV + kvh) * DH;
        float d = 0.f;
        #pragma unroll
        for (int x = 0; x < DH; x += 4) {
            float4 k4 = *(const float4*)(kr + x);
            d += sq[x] * k4.x + sq[x + 1] * k4.y + sq[x + 2] * k4.z + sq[x + 3] * k4.w;
        }
        sc[j] = d * scale;
    }
    __syncthreads();
    float m = -1e30f;
    for (int j = t; j < nk; j += 128) m = fmaxf(m, sc[j]);
    red[t] = m;
    __syncthreads();
    #pragma unroll
    for (int off = 64; off > 0; off >>= 1) {
        if (t < off) red[t] = fmaxf(red[t], red[t + off]);
        __syncthreads();
    }
    m = red[0];
    __syncthreads();
    float ssum = 0.f;
    for (int j = t; j < nk; j += 128) {
        float p = __expf(sc[j] - m);
        sc[j] = p;
        ssum += p;
    }
    red[t] = ssum;
    __syncthreads();
    #pragma unroll
    for (int off = 64; off > 0; off >>= 1) {
        if (t < off) red[t] += red[t + off];
        __syncthreads();
    }
    const float inv = 1.0f / red[0];
    float acc = 0.f;
    #pragma unroll 4
    for (int j = 0; j < nk; j++)
        acc += sc[j] * v[((size_t)j * NHKV + kvh) * DH + t];
    out[((size_t)qrow * NHQ + h) * DH + t] = acc * inv;
}

// ---------------- router logits + top-2 selection + expert grouping ----------------
__global__ void router_topk(const float* __restrict__ hbuf, const float* __restrict__ rw,
                            float* __restrict__ logits_out, int* __restrict__ cnt,
                            int* __restrict__ plist) {
    const int tok = blockIdx.x;
    const int tid = threadIdx.x;
    __shared__ float part[256];
    const int e = tid & 15, chunk = tid >> 4;
    const float* hr = hbuf + (size_t)tok * HDIM;
    float sum = 0.f;
    const int k0 = chunk * 128;
    for (int x = k0; x < k0 + 128; x++) sum += hr[x] * rw[(size_t)x * NE + e];
    part[tid] = sum;
    __syncthreads();
    if (tid < 16) {
        float s = 0.f;
        #pragma unroll
        for (int c = 0; c < 16; c++) s += part[c * 16 + tid];
        part[tid] = s;
    }
    __syncthreads();
    if (tid == 0) {
        float best = -1e30f; int bi = 0;
        for (int e2 = 0; e2 < 16; e2++) if (part[e2] > best) { best = part[e2]; bi = e2; }
        float best2 = -1e30f; int bi2 = 0;
        for (int e2 = 0; e2 < 16; e2++) if (e2 != bi && part[e2] > best2) { best2 = part[e2]; bi2 = e2; }
        int p0 = atomicAdd(&cnt[bi], 1);
        plist[bi * SEQ + p0] = tok * 2;
        int p1 = atomicAdd(&cnt[bi2], 1);
        plist[bi2 * SEQ + p1] = tok * 2 + 1;
    }
    if (tid < 16) logits_out[(size_t)tok * NE + tid] = part[tid];
}

// ---------------- tile map: tile -> (expert, row offset) ----------------
__global__ void tilemap(const int* __restrict__ cnt, int* __restrict__ te,
                        int* __restrict__ to, int* __restrict__ ntiles) {
    if (threadIdx.x == 0 && blockIdx.x == 0) {
        int n = 0;
        for (int e = 0; e < NE; e++) {
            int c = cnt[e];
            for (int off = 0; off < c; off += 64) { te[n] = e; to[n] = off; n++; }
        }
        *ntiles = n;
    }
}

// ---------------- MoE up GEMM (gather rows of h, per-expert W_up, silu epilogue) ----------------
// grid: (NI/64=12, MAX_TILES), block 256
__global__ void moe_up(const float* __restrict__ hbuf, const int* __restrict__ plist,
                       const int* __restrict__ cnt, const int* __restrict__ te,
                       const int* __restrict__ to, const int* __restrict__ ntiles,
                       const float* __restrict__ w_up, const float* __restrict__ b_up,
                       float* __restrict__ U) {
    const int t = blockIdx.y;
    if (t >= *ntiles) return;
    const int ex = te[t];
    const int r0 = to[t];
    const int cnt_e = cnt[ex];
    __shared__ int sp[64];
    __shared__ float As[64][17];
    __shared__ float Bs[16][65];
    const int tid = threadIdx.x;
    if (tid < 64) {
        int idx = r0 + tid;
        sp[tid] = (idx < cnt_e) ? plist[ex * SEQ + idx] : -1;
    }
    __syncthreads();
    const int ty = tid >> 4, tx = tid & 15;
    const int colBase = blockIdx.x * 64;
    const float* B = w_up + (size_t)ex * HDIM * NI;
    float acc[4][4] = {};
    for (int k0 = 0; k0 < HDIM; k0 += 16) {
        #pragma unroll
        for (int l = 0; l < 4; l++) {
            int e = tid + l * 256;
            int r = e >> 4, c = e & 15;
            int p = sp[r];
            int tok = (p >= 0) ? (p >> 1) : 0;
            As[r][c] = hbuf[(size_t)tok * HDIM + k0 + c];
        }
        #pragma unroll
        for (int l = 0; l < 4; l++) {
            int e = tid + l * 256;
            int r = e >> 6, c = e & 63;
            Bs[r][c] = B[(size_t)(k0 + r) * NI + colBase + c];
        }
        __syncthreads();
        #pragma unroll
        for (int kk = 0; kk < 16; kk++) {
            float a[4], b[4];
            #pragma unroll
            for (int i = 0; i < 4; i++) a[i] = As[ty * 4 + i][kk];
            #pragma unroll
            for (int j = 0; j < 4; j++) b[j] = Bs[kk][tx * 4 + j];
            #pragma unroll
            for (int i = 0; i < 4; i++)
                #pragma unroll
                for (int j = 0; j < 4; j++)
                    acc[i][j] += a[i] * b[j];
        }
        __syncthreads();
    }
    #pragma unroll
    for (int i = 0; i < 4; i++) {
        int p = sp[ty * 4 + i];
        if (p < 0) continue;
        #pragma unroll
        for (int j = 0; j < 4; j++) {
            int c = colBase + tx * 4 + j;
            float x = acc[i][j] + b_up[(size_t)ex * NI + c];
            U[(size_t)p * NI + c] = x / (1.0f + __expf(-x));
        }
    }
}

// ---------------- MoE down GEMM (gather rows of U, per-expert W_down, +b_down) ----------------
// grid: (HDIM/64=32, MAX_TILES), block 256
__global__ void moe_down(const float* __restrict__ U, const int* __restrict__ plist,
                         const int* __restrict__ cnt, const int* __restrict__ te,
                         const int* __restrict__ to, const int* __restrict__ ntiles,
                         const float* __restrict__ w_down, const float* __restrict__ b_down,
                         float* __restrict__ D) {
    const int t = blockIdx.y;
    if (t >= *ntiles) return;
    const int ex = te[t];
    const int r0 = to[t];
    const int cnt_e = cnt[ex];
    __shared__ int sp[64];
    __shared__ float As[64][17];
    __shared__ float Bs[16][65];
    const int tid = threadIdx.x;
    if (tid < 64) {
        int idx = r0 + tid;
        sp[tid] = (idx < cnt_e) ? plist[ex * SEQ + idx] : -1;
    }
    __syncthreads();
    const int ty = tid >> 4, tx = tid & 15;
    const int colBase = blockIdx.x * 64;
    const float* B = w_down + (size_t)ex * NI * HDIM;
    float acc[4][4] = {};
    for (int k0 = 0; k0 < NI; k0 += 16) {
        #pragma unroll
        for (int l = 0; l < 4; l++) {
            int e = tid + l * 256;
            int r = e >> 4, c = e & 15;
            int p = sp[r];
            int row = (p >= 0) ? p : 0;
            As[r][c] = U[(size_t)row * NI + k0 + c];
        }
        #pragma unroll
        for (int l = 0; l < 4; l++) {
            int e = tid + l * 256;
            int r = e >> 6, c = e & 63;
            Bs[r][c] = B[(size_t)(k0 + r) * HDIM + colBase + c];
        }
        __syncthreads();
        #pragma unroll
        for (int kk = 0; kk < 16; kk++) {
            float a[4], b[4];
            #pragma unroll
            for (int i = 0; i < 4; i++) a[i] = As[ty * 4 + i][kk];
            #pragma unroll
            for (int j = 0; j < 4; j++) b[j] = Bs[kk][tx * 4 + j];
            #pragma unroll
            for (int i = 0; i < 4; i++)
                #pragma unroll
                for (int j = 0; j < 4; j++)
                    acc[i][j] += a[i] * b[j];
        }
        __syncthreads();
    }
    #pragma unroll
    for (int i = 0; i < 4; i++) {
        int p = sp[ty * 4 + i];
        if (p < 0) continue;
        #pragma unroll
        for (int j = 0; j < 4; j++) {
            int c = colBase + tx * 4 + j;
            D[(size_t)p * HDIM + c] = acc[i][j] + b_down[(size_t)ex * HDIM + c];
        }
    }
}

// ---------------- combine: out = h + D[2t] + D[2t+1] ----------------
__global__ void combine(const float* __restrict__ D, float* __restrict__ h) {
    const int tok = blockIdx.x;
    const int tid = threadIdx.x;
    #pragma unroll
    for (int l = 0; l < 8; l++) {
        int x = tid + l * 256;
        h[(size_t)tok * HDIM + x] += D[(size_t)(2 * tok) * HDIM + x]
                                   + D[(size_t)(2 * tok + 1) * HDIM + x];
    }
}

extern "C" void kernel_launch(void* const* d_in, const int* in_sizes, int n_in,
                              void* d_out, int out_size, void* d_ws, size_t ws_size,
                              hipStream_t stream) {
    (void)in_sizes; (void)n_in; (void)out_size; (void)ws_size;
    const float* hidden   = (const float*)d_in[0];
    const float* wq       = (const float*)d_in[1];
    const float* wk       = (const float*)d_in[2];
    const float* wv       = (const float*)d_in[3];
    const float* wo       = (const float*)d_in[4];
    const float* q_scale  = (const float*)d_in[5];
    const float* k_scale  = (const float*)d_in[6];
    const float* router_w = (const float*)d_in[7];
    const float* w_up     = (const float*)d_in[8];
    const float* b_up     = (const float*)d_in[9];
    const float* w_down   = (const float*)d_in[10];
    const float* b_down   = (const float*)d_in[11];

    float* out = (float*)d_out;
    float* h_out      = out;
    float* logits_out = out + (size_t)SEQ * HDIM;

    // Workspace overlay (floats):
    //  phase 1 (attention): q[0..4.19M), k[4.19M..5.24M), v[5.24M..6.29M), attn[6.29M..10.49M)
    //  phase 2 (MoE):       D[0..8.39M), U[8.39M..11.53M)   (phase-1 buffers dead by then)
    //  lists: after 11.53M floats
    float* ws_f   = (float*)d_ws;
    float* q_ws    = ws_f;
    float* k_ws    = ws_f + (size_t)SEQ * HDIM;
    float* v_ws    = k_ws + (size_t)SEQ * NHKV * DH;
    float* attn_ws = v_ws + (size_t)SEQ * NHKV * DH;
    float* D_ws    = ws_f;                                   // 2*SEQ*HDIM
    float* U_ws    = ws_f + (size_t)2 * SEQ * HDIM;          // 2*SEQ*NI
    int*   ilists  = (int*)(U_ws + (size_t)2 * SEQ * NI);
    int* cnt_ws  = ilists;            // 16
    int* plist_ws = ilists + 16;      // NE*SEQ (upper bound; cnt_e <= SEQ)
    int* te_ws   = plist_ws + NE * SEQ;  // 128
    int* to_ws   = te_ws + 128;          // 128
    int* nt_ws   = to_ws + 128;          // 1

    // QKV projections
    gemm64<<<dim3(HDIM / 64, SEQ / 64), 256, 0, stream>>>(hidden, wq, q_ws, nullptr, SEQ, HDIM, HDIM);
    gemm64<<<dim3((NHKV * DH) / 64, SEQ / 64), 256, 0, stream>>>(hidden, wk, k_ws, nullptr, SEQ, NHKV * DH, HDIM);
    gemm64<<<dim3((NHKV * DH) / 64, SEQ / 64), 256, 0, stream>>>(hidden, wv, v_ws, nullptr, SEQ, NHKV * DH, HDIM);

    norm_rope<<<dim3(SEQ, NHQ + NHKV), 128, 0, stream>>>(q_ws, k_ws, q_scale, k_scale);

    attn<<<dim3(SEQ, NHQ), 128, 0, stream>>>(q_ws, k_ws, v_ws, attn_ws);

    // out-proj + residual -> h (stored in d_out)
    gemm64<<<dim3(HDIM / 64, SEQ / 64), 256, 0, stream>>>(attn_ws, wo, h_out, hidden, SEQ, HDIM, HDIM);

    // router + grouping
    hipMemsetAsync(cnt_ws, 0, NE * sizeof(int), stream);
    router_topk<<<dim3(SEQ), 256, 0, stream>>>(h_out, router_w, logits_out, cnt_ws, plist_ws);
    tilemap<<<1, 64, 0, stream>>>(cnt_ws, te_ws, to_ws, nt_ws);

    // expert-grouped MoE GEMMs
    moe_up<<<dim3(NI / 64, MAX_TILES), 256, 0, stream>>>(h_out, plist_ws, cnt_ws, te_ws, to_ws, nt_ws,
                                                         w_up, b_up, U_ws);
    moe_down<<<dim3(HDIM / 64, MAX_TILES), 256, 0, stream>>>(U_ws, plist_ws, cnt_ws, te_ws, to_ws, nt_ws,
                                                             w_down, b_down, D_ws);
    combine<<<dim3(SEQ), 256, 0, stream>>>(D_ws, h_out);
}

// Round 3
// 2421.275 us; speedup vs baseline: 5.1964x; 3.0374x over previous
//
#include <hip/hip_runtime.h>
#include <math.h>

#define SEQ 2048
#define HDIM 2048
#define NHQ 16
#define NHKV 4
#define DH 128
#define NE 16
#define NI 768
#define EPSV 1e-6f
#define MAX_TILES 80

// ---------------- generic tiled fp32 GEMM: C = A(MxK) @ B(KxN) (+ R) ----------------
__global__ void gemm64(const float* __restrict__ A, const float* __restrict__ B,
                       float* __restrict__ C, const float* __restrict__ R,
                       int M, int N, int K) {
    __shared__ float As[64][17];
    __shared__ float Bs[16][65];
    const int tid = threadIdx.x;
    const int ty = tid >> 4, tx = tid & 15;
    const int rowBase = blockIdx.y * 64;
    const int colBase = blockIdx.x * 64;
    float acc[4][4] = {};
    for (int k0 = 0; k0 < K; k0 += 16) {
        #pragma unroll
        for (int l = 0; l < 4; l++) {
            int e = tid + l * 256;
            int r = e >> 4, c = e & 15;
            As[r][c] = A[(size_t)(rowBase + r) * K + k0 + c];
        }
        #pragma unroll
        for (int l = 0; l < 4; l++) {
            int e = tid + l * 256;
            int r = e >> 6, c = e & 63;
            Bs[r][c] = B[(size_t)(k0 + r) * N + colBase + c];
        }
        __syncthreads();
        #pragma unroll
        for (int kk = 0; kk < 16; kk++) {
            float a[4], b[4];
            #pragma unroll
            for (int i = 0; i < 4; i++) a[i] = As[ty * 4 + i][kk];
            #pragma unroll
            for (int j = 0; j < 4; j++) b[j] = Bs[kk][tx * 4 + j];
            #pragma unroll
            for (int i = 0; i < 4; i++)
                #pragma unroll
                for (int j = 0; j < 4; j++)
                    acc[i][j] += a[i] * b[j];
        }
        __syncthreads();
    }
    #pragma unroll
    for (int i = 0; i < 4; i++) {
        int r = rowBase + ty * 4 + i;
        #pragma unroll
        for (int j = 0; j < 4; j++) {
            int c = colBase + tx * 4 + j;
            float v = acc[i][j];
            if (R) v += R[(size_t)r * N + c];
            C[(size_t)r * N + c] = v;
        }
    }
}

// ---------------- per-(seq,head) RMSNorm + RoPE, in place ----------------
__global__ void norm_rope(float* __restrict__ q, float* __restrict__ k,
                          const float* __restrict__ q_scale, const float* __restrict__ k_scale) {
    const int s = blockIdx.x;
    const int h = blockIdx.y;
    const int t = threadIdx.x;
    float* ptr;
    const float* scale;
    if (h < NHQ) { ptr = q + ((size_t)s * NHQ + h) * DH; scale = q_scale; }
    else         { ptr = k + ((size_t)s * NHKV + (h - NHQ)) * DH; scale = k_scale; }
    __shared__ float sh[DH];
    __shared__ float red[128];
    float x = ptr[t];
    red[t] = x * x;
    __syncthreads();
    #pragma unroll
    for (int off = 64; off > 0; off >>= 1) {
        if (t < off) red[t] += red[t + off];
        __syncthreads();
    }
    float var = red[0] * (1.0f / DH);
    float r = rsqrtf(var + EPSV);
    float xn = x * r * scale[t];
    sh[t] = xn;
    __syncthreads();
    int i = t & 63;
    float inv_freq = exp2f(-(float)i * 0.20762050593046014f);
    float ang = (float)s * inv_freq;
    float c = cosf(ang), sn = sinf(ang);
    float y;
    if (t < 64) y = xn * c - sh[t + 64] * sn;
    else        y = xn * c + sh[t - 64] * sn;
    ptr[t] = y;
}

// ---------------- flash attention: one block per (64-row Q tile, head) ----------------
// grid (32, 16), block 256.  Thread grid 16x16; rows r=ty+16i, S-cols c=tx+16j (2-way
// bank aliasing = free on 32-bank LDS).  K/V share one LDS buffer (disjoint lifetimes).
#define QT 64
#define KT 32
__global__ __launch_bounds__(256, 2)
void attn_flash(const float* __restrict__ q, const float* __restrict__ k,
                const float* __restrict__ v, float* __restrict__ out) {
    const int by = blockIdx.y;                    // head
    const int bx = blockIdx.x;
    const int qb = (by < 8) ? bx : (31 - bx);     // pair heavy+light tiles across CUs
    const int h = by;
    const int kvh = h >> 2;
    const int r0 = qb * QT;
    const int tid = threadIdx.x;
    const int ty = tid >> 4;
    const int tx = tid & 15;

    __shared__ float sQ[QT][132];
    __shared__ float sKV[KT][132];
    __shared__ float sP[QT][33];

    // stage Q tile (once): 64 rows x 32 float4
    #pragma unroll
    for (int l = 0; l < 8; l++) {
        int e4 = tid + l * 256;
        int r = e4 >> 5, c4 = e4 & 31;
        float4 val = *(const float4*)(q + ((size_t)(r0 + r) * NHQ + h) * DH + c4 * 4);
        *(float4*)&sQ[r][c4 * 4] = val;
    }

    float O[4][8];
    #pragma unroll
    for (int i = 0; i < 4; i++)
        #pragma unroll
        for (int j = 0; j < 8; j++) O[i][j] = 0.f;
    float mrow[4], lrow[4];
    #pragma unroll
    for (int i = 0; i < 4; i++) { mrow[i] = -3.0e38f; lrow[i] = 0.f; }

    const float scl = 0.08838834764831845f;  // 1/sqrt(128)
    const int nkt = 2 * qb + 2;

    for (int kt = 0; kt < nkt; kt++) {
        const int k0 = kt * KT;
        __syncthreads();  // prev PV done with sKV
        // stage K tile: 32 rows x 32 float4
        #pragma unroll
        for (int l = 0; l < 4; l++) {
            int e4 = tid + l * 256;
            int r = e4 >> 5, c4 = e4 & 31;
            float4 val = *(const float4*)(k + ((size_t)(k0 + r) * NHKV + kvh) * DH + c4 * 4);
            *(float4*)&sKV[r][c4 * 4] = val;
        }
        __syncthreads();

        // S = Q K^T  (64x32x128), float4 along d
        float S[4][2];
        #pragma unroll
        for (int i = 0; i < 4; i++) { S[i][0] = 0.f; S[i][1] = 0.f; }
        for (int d0 = 0; d0 < DH; d0 += 4) {
            float4 a4[4], b4[2];
            #pragma unroll
            for (int i = 0; i < 4; i++) a4[i] = *(const float4*)&sQ[ty + 16 * i][d0];
            #pragma unroll
            for (int j = 0; j < 2; j++) b4[j] = *(const float4*)&sKV[tx + 16 * j][d0];
            #pragma unroll
            for (int i = 0; i < 4; i++)
                #pragma unroll
                for (int j = 0; j < 2; j++)
                    S[i][j] += a4[i].x * b4[j].x + a4[i].y * b4[j].y
                             + a4[i].z * b4[j].z + a4[i].w * b4[j].w;
        }

        // causal mask + online softmax
        float tmax[4];
        #pragma unroll
        for (int i = 0; i < 4; i++) {
            tmax[i] = -3.0e38f;
            const int ra = r0 + ty + 16 * i;
            #pragma unroll
            for (int j = 0; j < 2; j++) {
                const int ca = k0 + tx + 16 * j;
                float s = (ca <= ra) ? S[i][j] * scl : -3.0e38f;
                S[i][j] = s;
                tmax[i] = fmaxf(tmax[i], s);
            }
        }
        #pragma unroll
        for (int i = 0; i < 4; i++) {
            #pragma unroll
            for (int w = 1; w < 16; w <<= 1)
                tmax[i] = fmaxf(tmax[i], __shfl_xor(tmax[i], w));
            float newm = fmaxf(mrow[i], tmax[i]);
            float alpha = __expf(mrow[i] - newm);
            float psum = 0.f;
            #pragma unroll
            for (int j = 0; j < 2; j++) {
                float p = __expf(S[i][j] - newm);
                S[i][j] = p;
                psum += p;
            }
            #pragma unroll
            for (int w = 1; w < 16; w <<= 1) psum += __shfl_xor(psum, w);
            lrow[i] = lrow[i] * alpha + psum;
            mrow[i] = newm;
            #pragma unroll
            for (int j = 0; j < 8; j++) O[i][j] *= alpha;
            #pragma unroll
            for (int j = 0; j < 2; j++) sP[ty + 16 * i][tx + 16 * j] = S[i][j];
        }
        __syncthreads();  // sP written; sKV (K) free

        // stage V tile into sKV
        #pragma unroll
        for (int l = 0; l < 4; l++) {
            int e4 = tid + l * 256;
            int r = e4 >> 5, c4 = e4 & 31;
            float4 val = *(const float4*)(v + ((size_t)(k0 + r) * NHKV + kvh) * DH + c4 * 4);
            *(float4*)&sKV[r][c4 * 4] = val;
        }
        __syncthreads();

        // O += P V  (64x128x32)
        for (int kk = 0; kk < KT; kk++) {
            float a[4], b[8];
            #pragma unroll
            for (int i = 0; i < 4; i++) a[i] = sP[ty + 16 * i][kk];
            #pragma unroll
            for (int j = 0; j < 8; j++) b[j] = sKV[kk][tx + 16 * j];
            #pragma unroll
            for (int i = 0; i < 4; i++)
                #pragma unroll
                for (int j = 0; j < 8; j++)
                    O[i][j] += a[i] * b[j];
        }
    }

    #pragma unroll
    for (int i = 0; i < 4; i++) {
        const float inv = 1.0f / lrow[i];
        const int r = r0 + ty + 16 * i;
        #pragma unroll
        for (int j = 0; j < 8; j++)
            out[((size_t)r * NHQ + h) * DH + tx + 16 * j] = O[i][j] * inv;
    }
}

// ---------------- router logits + top-2 selection + expert grouping ----------------
__global__ void router_topk(const float* __restrict__ hbuf, const float* __restrict__ rw,
                            float* __restrict__ logits_out, int* __restrict__ cnt,
                            int* __restrict__ plist) {
    const int tok = blockIdx.x;
    const int tid = threadIdx.x;
    __shared__ float part[256];
    const int e = tid & 15, chunk = tid >> 4;
    const float* hr = hbuf + (size_t)tok * HDIM;
    float sum = 0.f;
    const int k0 = chunk * 128;
    for (int x = k0; x < k0 + 128; x++) sum += hr[x] * rw[(size_t)x * NE + e];
    part[tid] = sum;
    __syncthreads();
    if (tid < 16) {
        float s = 0.f;
        #pragma unroll
        for (int c = 0; c < 16; c++) s += part[c * 16 + tid];
        part[tid] = s;
    }
    __syncthreads();
    if (tid == 0) {
        float best = -1e30f; int bi = 0;
        for (int e2 = 0; e2 < 16; e2++) if (part[e2] > best) { best = part[e2]; bi = e2; }
        float best2 = -1e30f; int bi2 = 0;
        for (int e2 = 0; e2 < 16; e2++) if (e2 != bi && part[e2] > best2) { best2 = part[e2]; bi2 = e2; }
        int p0 = atomicAdd(&cnt[bi], 1);
        plist[bi * SEQ + p0] = tok * 2;
        int p1 = atomicAdd(&cnt[bi2], 1);
        plist[bi2 * SEQ + p1] = tok * 2 + 1;
    }
    if (tid < 16) logits_out[(size_t)tok * NE + tid] = part[tid];
}

// ---------------- tile map: tile -> (expert, row offset) ----------------
__global__ void tilemap(const int* __restrict__ cnt, int* __restrict__ te,
                        int* __restrict__ to, int* __restrict__ ntiles) {
    if (threadIdx.x == 0 && blockIdx.x == 0) {
        int n = 0;
        for (int e = 0; e < NE; e++) {
            int c = cnt[e];
            for (int off = 0; off < c; off += 64) { te[n] = e; to[n] = off; n++; }
        }
        *ntiles = n;
    }
}

// ---------------- MoE up GEMM (gather rows of h, per-expert W_up, silu epilogue) ----------------
__global__ void moe_up(const float* __restrict__ hbuf, const int* __restrict__ plist,
                       const int* __restrict__ cnt, const int* __restrict__ te,
                       const int* __restrict__ to, const int* __restrict__ ntiles,
                       const float* __restrict__ w_up, const float* __restrict__ b_up,
                       float* __restrict__ U) {
    const int t = blockIdx.y;
    if (t >= *ntiles) return;
    const int ex = te[t];
    const int r0 = to[t];
    const int cnt_e = cnt[ex];
    __shared__ int sp[64];
    __shared__ float As[64][17];
    __shared__ float Bs[16][65];
    const int tid = threadIdx.x;
    if (tid < 64) {
        int idx = r0 + tid;
        sp[tid] = (idx < cnt_e) ? plist[ex * SEQ + idx] : -1;
    }
    __syncthreads();
    const int ty = tid >> 4, tx = tid & 15;
    const int colBase = blockIdx.x * 64;
    const float* B = w_up + (size_t)ex * HDIM * NI;
    float acc[4][4] = {};
    for (int k0 = 0; k0 < HDIM; k0 += 16) {
        #pragma unroll
        for (int l = 0; l < 4; l++) {
            int e = tid + l * 256;
            int r = e >> 4, c = e & 15;
            int p = sp[r];
            int tok = (p >= 0) ? (p >> 1) : 0;
            As[r][c] = hbuf[(size_t)tok * HDIM + k0 + c];
        }
        #pragma unroll
        for (int l = 0; l < 4; l++) {
            int e = tid + l * 256;
            int r = e >> 6, c = e & 63;
            Bs[r][c] = B[(size_t)(k0 + r) * NI + colBase + c];
        }
        __syncthreads();
        #pragma unroll
        for (int kk = 0; kk < 16; kk++) {
            float a[4], b[4];
            #pragma unroll
            for (int i = 0; i < 4; i++) a[i] = As[ty * 4 + i][kk];
            #pragma unroll
            for (int j = 0; j < 4; j++) b[j] = Bs[kk][tx * 4 + j];
            #pragma unroll
            for (int i = 0; i < 4; i++)
                #pragma unroll
                for (int j = 0; j < 4; j++)
                    acc[i][j] += a[i] * b[j];
        }
        __syncthreads();
    }
    #pragma unroll
    for (int i = 0; i < 4; i++) {
        int p = sp[ty * 4 + i];
        if (p < 0) continue;
        #pragma unroll
        for (int j = 0; j < 4; j++) {
            int c = colBase + tx * 4 + j;
            float x = acc[i][j] + b_up[(size_t)ex * NI + c];
            U[(size_t)p * NI + c] = x / (1.0f + __expf(-x));
        }
    }
}

// ---------------- MoE down GEMM (gather rows of U, per-expert W_down, +b_down) ----------------
__global__ void moe_down(const float* __restrict__ U, const int* __restrict__ plist,
                         const int* __restrict__ cnt, const int* __restrict__ te,
                         const int* __restrict__ to, const int* __restrict__ ntiles,
                         const float* __restrict__ w_down, const float* __restrict__ b_down,
                         float* __restrict__ D) {
    const int t = blockIdx.y;
    if (t >= *ntiles) return;
    const int ex = te[t];
    const int r0 = to[t];
    const int cnt_e = cnt[ex];
    __shared__ int sp[64];
    __shared__ float As[64][17];
    __shared__ float Bs[16][65];
    const int tid = threadIdx.x;
    if (tid < 64) {
        int idx = r0 + tid;
        sp[tid] = (idx < cnt_e) ? plist[ex * SEQ + idx] : -1;
    }
    __syncthreads();
    const int ty = tid >> 4, tx = tid & 15;
    const int colBase = blockIdx.x * 64;
    const float* B = w_down + (size_t)ex * NI * HDIM;
    float acc[4][4] = {};
    for (int k0 = 0; k0 < NI; k0 += 16) {
        #pragma unroll
        for (int l = 0; l < 4; l++) {
            int e = tid + l * 256;
            int r = e >> 4, c = e & 15;
            int p = sp[r];
            int row = (p >= 0) ? p : 0;
            As[r][c] = U[(size_t)row * NI + k0 + c];
        }
        #pragma unroll
        for (int l = 0; l < 4; l++) {
            int e = tid + l * 256;
            int r = e >> 6, c = e & 63;
            Bs[r][c] = B[(size_t)(k0 + r) * HDIM + colBase + c];
        }
        __syncthreads();
        #pragma unroll
        for (int kk = 0; kk < 16; kk++) {
            float a[4], b[4];
            #pragma unroll
            for (int i = 0; i < 4; i++) a[i] = As[ty * 4 + i][kk];
            #pragma unroll
            for (int j = 0; j < 4; j++) b[j] = Bs[kk][tx * 4 + j];
            #pragma unroll
            for (int i = 0; i < 4; i++)
                #pragma unroll
                for (int j = 0; j < 4; j++)
                    acc[i][j] += a[i] * b[j];
        }
        __syncthreads();
    }
    #pragma unroll
    for (int i = 0; i < 4; i++) {
        int p = sp[ty * 4 + i];
        if (p < 0) continue;
        #pragma unroll
        for (int j = 0; j < 4; j++) {
            int c = colBase + tx * 4 + j;
            D[(size_t)p * HDIM + c] = acc[i][j] + b_down[(size_t)ex * HDIM + c];
        }
    }
}

// ---------------- combine: out = h + D[2t] + D[2t+1] ----------------
__global__ void combine(const float* __restrict__ D, float* __restrict__ h) {
    const int tok = blockIdx.x;
    const int tid = threadIdx.x;
    #pragma unroll
    for (int l = 0; l < 8; l++) {
        int x = tid + l * 256;
        h[(size_t)tok * HDIM + x] += D[(size_t)(2 * tok) * HDIM + x]
                                   + D[(size_t)(2 * tok + 1) * HDIM + x];
    }
}

extern "C" void kernel_launch(void* const* d_in, const int* in_sizes, int n_in,
                              void* d_out, int out_size, void* d_ws, size_t ws_size,
                              hipStream_t stream) {
    (void)in_sizes; (void)n_in; (void)out_size; (void)ws_size;
    const float* hidden   = (const float*)d_in[0];
    const float* wq       = (const float*)d_in[1];
    const float* wk       = (const float*)d_in[2];
    const float* wv       = (const float*)d_in[3];
    const float* wo       = (const float*)d_in[4];
    const float* q_scale  = (const float*)d_in[5];
    const float* k_scale  = (const float*)d_in[6];
    const float* router_w = (const float*)d_in[7];
    const float* w_up     = (const float*)d_in[8];
    const float* b_up     = (const float*)d_in[9];
    const float* w_down   = (const float*)d_in[10];
    const float* b_down   = (const float*)d_in[11];

    float* out = (float*)d_out;
    float* h_out      = out;
    float* logits_out = out + (size_t)SEQ * HDIM;

    float* ws_f   = (float*)d_ws;
    float* q_ws    = ws_f;
    float* k_ws    = ws_f + (size_t)SEQ * HDIM;
    float* v_ws    = k_ws + (size_t)SEQ * NHKV * DH;
    float* attn_ws = v_ws + (size_t)SEQ * NHKV * DH;
    float* D_ws    = ws_f;                                   // 2*SEQ*HDIM (phase 2)
    float* U_ws    = ws_f + (size_t)2 * SEQ * HDIM;          // 2*SEQ*NI
    int*   ilists  = (int*)(U_ws + (size_t)2 * SEQ * NI);
    int* cnt_ws   = ilists;
    int* plist_ws = ilists + 16;
    int* te_ws    = plist_ws + NE * SEQ;
    int* to_ws    = te_ws + 128;
    int* nt_ws    = to_ws + 128;

    gemm64<<<dim3(HDIM / 64, SEQ / 64), 256, 0, stream>>>(hidden, wq, q_ws, nullptr, SEQ, HDIM, HDIM);
    gemm64<<<dim3((NHKV * DH) / 64, SEQ / 64), 256, 0, stream>>>(hidden, wk, k_ws, nullptr, SEQ, NHKV * DH, HDIM);
    gemm64<<<dim3((NHKV * DH) / 64, SEQ / 64), 256, 0, stream>>>(hidden, wv, v_ws, nullptr, SEQ, NHKV * DH, HDIM);

    norm_rope<<<dim3(SEQ, NHQ + NHKV), 128, 0, stream>>>(q_ws, k_ws, q_scale, k_scale);

    attn_flash<<<dim3(SEQ / QT, NHQ), 256, 0, stream>>>(q_ws, k_ws, v_ws, attn_ws);

    gemm64<<<dim3(HDIM / 64, SEQ / 64), 256, 0, stream>>>(attn_ws, wo, h_out, hidden, SEQ, HDIM, HDIM);

    hipMemsetAsync(cnt_ws, 0, NE * sizeof(int), stream);
    router_topk<<<dim3(SEQ), 256, 0, stream>>>(h_out, router_w, logits_out, cnt_ws, plist_ws);
    tilemap<<<1, 64, 0, stream>>>(cnt_ws, te_ws, to_ws, nt_ws);

    moe_up<<<dim3(NI / 64, MAX_TILES), 256, 0, stream>>>(h_out, plist_ws, cnt_ws, te_ws, to_ws, nt_ws,
                                                         w_up, b_up, U_ws);
    moe_down<<<dim3(HDIM / 64, MAX_TILES), 256, 0, stream>>>(U_ws, plist_ws, cnt_ws, te_ws, to_ws, nt_ws,
                                                             w_down, b_down, D_ws);
    combine<<<dim3(SEQ), 256, 0, stream>>>(D_ws, h_out);
}

// Round 4
// 1143.714 us; speedup vs baseline: 11.0008x; 2.1170x over previous
//
#include <hip/hip_runtime.h>
#include <math.h>

#define SEQ 2048
#define HDIM 2048
#define NHQ 16
#define NHKV 4
#define DH 128
#define NE 16
#define NI 768
#define EPSV 1e-6f
#define QKVS 3072           // row stride of fused qkv fp32 buffer
#define MOE_TILES 48        // max 128-row tiles across experts: 32 + 15 < 48

typedef __attribute__((ext_vector_type(8))) __bf16 bf16x8;
typedef __attribute__((ext_vector_type(4))) float f32x4;
typedef unsigned short ushort_t;

__device__ __forceinline__ ushort_t f2bf(float f) {
    union { float f; unsigned int u; } v; v.f = f;
    unsigned int u = v.u;
    unsigned int r = (u + 0x7FFFu + ((u >> 16) & 1u)) >> 16;
    return (ushort_t)r;
}
__device__ __forceinline__ float bf2f(ushort_t b) {
    union { unsigned int u; float f; } v; v.u = ((unsigned int)b) << 16;
    return v.f;
}
__device__ __forceinline__ void async16(const ushort_t* g, ushort_t* l) {
    __builtin_amdgcn_global_load_lds(
        (const __attribute__((address_space(1))) void*)g,
        (__attribute__((address_space(3))) void*)l, 16, 0, 0);
}

// ---------------- fp32 -> (hi,lo) bf16 split, elementwise (for hidden) ----------------
__global__ void split_cvt(const float* __restrict__ in, ushort_t* __restrict__ hi,
                          ushort_t* __restrict__ lo) {
    int i = blockIdx.x * 256 + threadIdx.x;
    float4 v = ((const float4*)in)[i];
    ushort_t h0 = f2bf(v.x), h1 = f2bf(v.y), h2 = f2bf(v.z), h3 = f2bf(v.w);
    ushort4 h = make_ushort4(h0, h1, h2, h3);
    ushort4 l = make_ushort4(f2bf(v.x - bf2f(h0)), f2bf(v.y - bf2f(h1)),
                             f2bf(v.z - bf2f(h2)), f2bf(v.w - bf2f(h3)));
    ((ushort4*)hi)[i] = h;
    ((ushort4*)lo)[i] = l;
}

// ---------------- transpose K×N fp32 -> N×K (hi,lo) bf16 ----------------
__global__ void transpose_split(const float* __restrict__ in, ushort_t* __restrict__ hi,
                                ushort_t* __restrict__ lo, int K, int N) {
    __shared__ float tls[32][33];
    int tx = threadIdx.x & 31, ty = threadIdx.x >> 5;
    size_t k0 = (size_t)blockIdx.y * 32, n0 = (size_t)blockIdx.x * 32;
    #pragma unroll
    for (int i = 0; i < 32; i += 8) tls[ty + i][tx] = in[(k0 + ty + i) * N + n0 + tx];
    __syncthreads();
    #pragma unroll
    for (int i = 0; i < 32; i += 8) {
        float v = tls[tx][ty + i];
        ushort_t h = f2bf(v);
        size_t o = (n0 + ty + i) * K + k0 + tx;
        hi[o] = h;
        lo[o] = f2bf(v - bf2f(h));
    }
}

// ---------------- transpose K×N fp32 -> N×K bf16, batched over z ----------------
__global__ void transpose_cvt(const float* __restrict__ in, ushort_t* __restrict__ out,
                              int K, int N) {
    const float* ib = in + (size_t)blockIdx.z * K * N;
    ushort_t* ob = out + (size_t)blockIdx.z * K * N;
    __shared__ float tls[32][33];
    int tx = threadIdx.x & 31, ty = threadIdx.x >> 5;
    size_t k0 = (size_t)blockIdx.y * 32, n0 = (size_t)blockIdx.x * 32;
    #pragma unroll
    for (int i = 0; i < 32; i += 8) tls[ty + i][tx] = ib[(k0 + ty + i) * N + n0 + tx];
    __syncthreads();
    #pragma unroll
    for (int i = 0; i < 32; i += 8)
        ob[(n0 + ty + i) * K + k0 + tx] = f2bf(tls[tx][ty + i]);
}

// ---------------- split-bf16 MFMA GEMM: C = A(M×K) @ Bt^T (+R), ~fp32 precision ----------------
// A as (hi,lo) row-major M×K; Bt as (hi,lo) row-major N×K. 128×128 tile, BK=32, 4 waves.
#define BM 128
#define BN 128
#define BK 32
__global__ __launch_bounds__(256, 2)
void gemm_split(const ushort_t* __restrict__ Ahi, const ushort_t* __restrict__ Alo,
                const ushort_t* __restrict__ Bhi, const ushort_t* __restrict__ Blo,
                float* __restrict__ C, int ldc,
                const float* __restrict__ R, ushort_t* __restrict__ Cbf,
                int N, int K) {
    __shared__ ushort_t sAh[BM * BK], sAl[BM * BK], sBh[BN * BK], sBl[BN * BK];
    const int tid = threadIdx.x;
    const int wave = tid >> 6, lane = tid & 63;
    const int wy = wave >> 1, wx = wave & 1;
    const int quad = lane >> 4, m16 = lane & 15;
    const size_t rowBase = (size_t)blockIdx.y * BM;
    const size_t colBase = (size_t)blockIdx.x * BN;
    const int srow = wave * 32 + (lane >> 2);
    const int scol = (lane & 3) * 8;
    const size_t aoff0 = (rowBase + srow) * K + scol;
    const size_t aoff1 = aoff0 + (size_t)16 * K;
    const size_t boff0 = (colBase + srow) * K + scol;
    const size_t boff1 = boff0 + (size_t)16 * K;
    ushort_t* dA0 = &sAh[(wave * 32) * BK];
    ushort_t* dA1 = &sAh[(wave * 32 + 16) * BK];
    ushort_t* dAl0 = &sAl[(wave * 32) * BK];
    ushort_t* dAl1 = &sAl[(wave * 32 + 16) * BK];
    ushort_t* dB0 = &sBh[(wave * 32) * BK];
    ushort_t* dB1 = &sBh[(wave * 32 + 16) * BK];
    ushort_t* dBl0 = &sBl[(wave * 32) * BK];
    ushort_t* dBl1 = &sBl[(wave * 32 + 16) * BK];
    f32x4 acc[4][4] = {};
    for (int k0 = 0; k0 < K; k0 += BK) {
        __syncthreads();
        async16(Ahi + aoff0 + k0, dA0);
        async16(Ahi + aoff1 + k0, dA1);
        async16(Alo + aoff0 + k0, dAl0);
        async16(Alo + aoff1 + k0, dAl1);
        async16(Bhi + boff0 + k0, dB0);
        async16(Bhi + boff1 + k0, dB1);
        async16(Blo + boff0 + k0, dBl0);
        async16(Blo + boff1 + k0, dBl1);
        __syncthreads();
        bf16x8 ah[4], al[4], bh[4], bl[4];
        #pragma unroll
        for (int i = 0; i < 4; i++) {
            ah[i] = *(const bf16x8*)&sAh[(wy * 64 + i * 16 + m16) * BK + quad * 8];
            al[i] = *(const bf16x8*)&sAl[(wy * 64 + i * 16 + m16) * BK + quad * 8];
        }
        #pragma unroll
        for (int j = 0; j < 4; j++) {
            bh[j] = *(const bf16x8*)&sBh[(wx * 64 + j * 16 + m16) * BK + quad * 8];
            bl[j] = *(const bf16x8*)&sBl[(wx * 64 + j * 16 + m16) * BK + quad * 8];
        }
        #pragma unroll
        for (int i = 0; i < 4; i++)
            #pragma unroll
            for (int j = 0; j < 4; j++) {
                acc[i][j] = __builtin_amdgcn_mfma_f32_16x16x32_bf16(ah[i], bh[j], acc[i][j], 0, 0, 0);
                acc[i][j] = __builtin_amdgcn_mfma_f32_16x16x32_bf16(ah[i], bl[j], acc[i][j], 0, 0, 0);
                acc[i][j] = __builtin_amdgcn_mfma_f32_16x16x32_bf16(al[i], bh[j], acc[i][j], 0, 0, 0);
            }
    }
    #pragma unroll
    for (int i = 0; i < 4; i++)
        #pragma unroll
        for (int j = 0; j < 4; j++)
            #pragma unroll
            for (int r = 0; r < 4; r++) {
                size_t row = rowBase + wy * 64 + i * 16 + quad * 4 + r;
                size_t col = colBase + wx * 64 + j * 16 + m16;
                float v = acc[i][j][r];
                if (R) v += R[row * N + col];
                C[row * ldc + col] = v;
                if (Cbf) Cbf[row * N + col] = f2bf(v);
            }
}

// ---------------- per-(seq,head) RMSNorm + RoPE on fused qkv buffer ----------------
__global__ void norm_rope(float* __restrict__ qkv, const float* __restrict__ q_scale,
                          const float* __restrict__ k_scale) {
    const int s = blockIdx.x;
    const int h = blockIdx.y;
    const int t = threadIdx.x;
    float* ptr;
    const float* scale;
    if (h < NHQ) { ptr = qkv + (size_t)s * QKVS + h * DH; scale = q_scale; }
    else         { ptr = qkv + (size_t)s * QKVS + 2048 + (h - NHQ) * DH; scale = k_scale; }
    __shared__ float sh[DH];
    __shared__ float red[128];
    float x = ptr[t];
    red[t] = x * x;
    __syncthreads();
    #pragma unroll
    for (int off = 64; off > 0; off >>= 1) {
        if (t < off) red[t] += red[t + off];
        __syncthreads();
    }
    float var = red[0] * (1.0f / DH);
    float r = rsqrtf(var + EPSV);
    float xn = x * r * scale[t];
    sh[t] = xn;
    __syncthreads();
    int i = t & 63;
    float inv_freq = exp2f(-(float)i * 0.20762050593046014f);
    float ang = (float)s * inv_freq;
    float c = cosf(ang), sn = sinf(ang);
    float y;
    if (t < 64) y = xn * c - sh[t + 64] * sn;
    else        y = xn * c + sh[t - 64] * sn;
    ptr[t] = y;
}

// ---------------- flash attention on fused qkv; writes split-bf16 output ----------------
#define QT 64
#define KT 32
__global__ __launch_bounds__(256, 2)
void attn_flash(const float* __restrict__ qkv, ushort_t* __restrict__ ohi,
                ushort_t* __restrict__ olo) {
    const int by = blockIdx.y;
    const int bx = blockIdx.x;
    const int qb = (by < 8) ? bx : (31 - bx);
    const int h = by;
    const int kvh = h >> 2;
    const int r0 = qb * QT;
    const int tid = threadIdx.x;
    const int ty = tid >> 4;
    const int tx = tid & 15;

    __shared__ float sQ[QT][132];
    __shared__ float sKV[KT][132];
    __shared__ float sP[QT][33];

    #pragma unroll
    for (int l = 0; l < 8; l++) {
        int e4 = tid + l * 256;
        int r = e4 >> 5, c4 = e4 & 31;
        float4 val = *(const float4*)(qkv + (size_t)(r0 + r) * QKVS + h * DH + c4 * 4);
        *(float4*)&sQ[r][c4 * 4] = val;
    }

    float O[4][8];
    #pragma unroll
    for (int i = 0; i < 4; i++)
        #pragma unroll
        for (int j = 0; j < 8; j++) O[i][j] = 0.f;
    float mrow[4], lrow[4];
    #pragma unroll
    for (int i = 0; i < 4; i++) { mrow[i] = -3.0e38f; lrow[i] = 0.f; }

    const float scl = 0.08838834764831845f;
    const int nkt = 2 * qb + 2;

    for (int kt = 0; kt < nkt; kt++) {
        const int k0 = kt * KT;
        __syncthreads();
        #pragma unroll
        for (int l = 0; l < 4; l++) {
            int e4 = tid + l * 256;
            int r = e4 >> 5, c4 = e4 & 31;
            float4 val = *(const float4*)(qkv + (size_t)(k0 + r) * QKVS + 2048 + kvh * DH + c4 * 4);
            *(float4*)&sKV[r][c4 * 4] = val;
        }
        __syncthreads();

        float S[4][2];
        #pragma unroll
        for (int i = 0; i < 4; i++) { S[i][0] = 0.f; S[i][1] = 0.f; }
        for (int d0 = 0; d0 < DH; d0 += 4) {
            float4 a4[4], b4[2];
            #pragma unroll
            for (int i = 0; i < 4; i++) a4[i] = *(const float4*)&sQ[ty + 16 * i][d0];
            #pragma unroll
            for (int j = 0; j < 2; j++) b4[j] = *(const float4*)&sKV[tx + 16 * j][d0];
            #pragma unroll
            for (int i = 0; i < 4; i++)
                #pragma unroll
                for (int j = 0; j < 2; j++)
                    S[i][j] += a4[i].x * b4[j].x + a4[i].y * b4[j].y
                             + a4[i].z * b4[j].z + a4[i].w * b4[j].w;
        }

        float tmax[4];
        #pragma unroll
        for (int i = 0; i < 4; i++) {
            tmax[i] = -3.0e38f;
            const int ra = r0 + ty + 16 * i;
            #pragma unroll
            for (int j = 0; j < 2; j++) {
                const int ca = k0 + tx + 16 * j;
                float s = (ca <= ra) ? S[i][j] * scl : -3.0e38f;
                S[i][j] = s;
                tmax[i] = fmaxf(tmax[i], s);
            }
        }
        #pragma unroll
        for (int i = 0; i < 4; i++) {
            #pragma unroll
            for (int w = 1; w < 16; w <<= 1)
                tmax[i] = fmaxf(tmax[i], __shfl_xor(tmax[i], w));
            float newm = fmaxf(mrow[i], tmax[i]);
            float alpha = __expf(mrow[i] - newm);
            float psum = 0.f;
            #pragma unroll
            for (int j = 0; j < 2; j++) {
                float p = __expf(S[i][j] - newm);
                S[i][j] = p;
                psum += p;
            }
            #pragma unroll
            for (int w = 1; w < 16; w <<= 1) psum += __shfl_xor(psum, w);
            lrow[i] = lrow[i] * alpha + psum;
            mrow[i] = newm;
            #pragma unroll
            for (int j = 0; j < 8; j++) O[i][j] *= alpha;
            #pragma unroll
            for (int j = 0; j < 2; j++) sP[ty + 16 * i][tx + 16 * j] = S[i][j];
        }
        __syncthreads();

        #pragma unroll
        for (int l = 0; l < 4; l++) {
            int e4 = tid + l * 256;
            int r = e4 >> 5, c4 = e4 & 31;
            float4 val = *(const float4*)(qkv + (size_t)(k0 + r) * QKVS + 2560 + kvh * DH + c4 * 4);
            *(float4*)&sKV[r][c4 * 4] = val;
        }
        __syncthreads();

        for (int kk = 0; kk < KT; kk++) {
            float a[4], b[8];
            #pragma unroll
            for (int i = 0; i < 4; i++) a[i] = sP[ty + 16 * i][kk];
            #pragma unroll
            for (int j = 0; j < 8; j++) b[j] = sKV[kk][tx + 16 * j];
            #pragma unroll
            for (int i = 0; i < 4; i++)
                #pragma unroll
                for (int j = 0; j < 8; j++)
                    O[i][j] += a[i] * b[j];
        }
    }

    #pragma unroll
    for (int i = 0; i < 4; i++) {
        const float inv = 1.0f / lrow[i];
        const size_t r = r0 + ty + 16 * i;
        #pragma unroll
        for (int j = 0; j < 8; j++) {
            float val = O[i][j] * inv;
            size_t o = r * (NHQ * DH) + h * DH + tx + 16 * j;
            ushort_t hh = f2bf(val);
            ohi[o] = hh;
            olo[o] = f2bf(val - bf2f(hh));
        }
    }
}

// ---------------- router logits + top-2 + expert grouping ----------------
__global__ void router_topk(const float* __restrict__ hbuf, const float* __restrict__ rw,
                            float* __restrict__ logits_out, int* __restrict__ cnt,
                            int* __restrict__ plist) {
    const int tok = blockIdx.x;
    const int tid = threadIdx.x;
    __shared__ float part[256];
    const int e = tid & 15, chunk = tid >> 4;
    const float* hr = hbuf + (size_t)tok * HDIM;
    float sum = 0.f;
    const int k0 = chunk * 128;
    for (int x = k0; x < k0 + 128; x++) sum += hr[x] * rw[(size_t)x * NE + e];
    part[tid] = sum;
    __syncthreads();
    if (tid < 16) {
        float s = 0.f;
        #pragma unroll
        for (int c = 0; c < 16; c++) s += part[c * 16 + tid];
        part[tid] = s;
    }
    __syncthreads();
    if (tid == 0) {
        float best = -1e30f; int bi = 0;
        for (int e2 = 0; e2 < 16; e2++) if (part[e2] > best) { best = part[e2]; bi = e2; }
        float best2 = -1e30f; int bi2 = 0;
        for (int e2 = 0; e2 < 16; e2++) if (e2 != bi && part[e2] > best2) { best2 = part[e2]; bi2 = e2; }
        int p0 = atomicAdd(&cnt[bi], 1);
        plist[bi * SEQ + p0] = tok * 2;
        int p1 = atomicAdd(&cnt[bi2], 1);
        plist[bi2 * SEQ + p1] = tok * 2 + 1;
    }
    if (tid < 16) logits_out[(size_t)tok * NE + tid] = part[tid];
}

// ---------------- tile map (128-row tiles) ----------------
__global__ void tilemap(const int* __restrict__ cnt, int* __restrict__ te,
                        int* __restrict__ to, int* __restrict__ ntiles) {
    if (threadIdx.x == 0 && blockIdx.x == 0) {
        int n = 0;
        for (int e = 0; e < NE; e++) {
            int c = cnt[e];
            for (int off = 0; off < c; off += BM) { te[n] = e; to[n] = off; n++; }
        }
        *ntiles = n;
    }
}

// ---------------- MoE up: gather-A bf16 MFMA GEMM, silu epilogue -> U bf16 ----------------
__global__ __launch_bounds__(256, 2)
void moe_up_mfma(const ushort_t* __restrict__ hbf, const int* __restrict__ plist,
                 const int* __restrict__ cnt, const int* __restrict__ te,
                 const int* __restrict__ to, const int* __restrict__ nt,
                 const ushort_t* __restrict__ wupt, const float* __restrict__ b_up,
                 ushort_t* __restrict__ U) {
    const int t = blockIdx.y;
    if (t >= *nt) return;
    const int ex = te[t], r0 = to[t], cnt_e = cnt[ex];
    __shared__ int sp[BM];
    __shared__ ushort_t sA[BM * BK], sB[BN * BK];
    const int tid = threadIdx.x;
    if (tid < BM) {
        int idx = r0 + tid;
        sp[tid] = (idx < cnt_e) ? plist[ex * SEQ + idx] : 0;
    }
    __syncthreads();
    const int wave = tid >> 6, lane = tid & 63;
    const int wy = wave >> 1, wx = wave & 1;
    const int quad = lane >> 4, m16 = lane & 15;
    const int srow = wave * 32 + (lane >> 2);
    const int scol = (lane & 3) * 8;
    const int p0 = sp[srow], p1 = sp[srow + 16];
    const ushort_t* Ag0 = hbf + (size_t)(p0 >> 1) * HDIM + scol;
    const ushort_t* Ag1 = hbf + (size_t)(p1 >> 1) * HDIM + scol;
    const size_t colBase = (size_t)blockIdx.x * BN;
    const ushort_t* Bt = wupt + (size_t)ex * HDIM * NI;
    const ushort_t* Bg0 = Bt + (colBase + srow) * HDIM + scol;
    const ushort_t* Bg1 = Bg0 + (size_t)16 * HDIM;
    ushort_t* dA0 = &sA[(wave * 32) * BK];
    ushort_t* dA1 = &sA[(wave * 32 + 16) * BK];
    ushort_t* dB0 = &sB[(wave * 32) * BK];
    ushort_t* dB1 = &sB[(wave * 32 + 16) * BK];
    f32x4 acc[4][4] = {};
    for (int k0 = 0; k0 < HDIM; k0 += BK) {
        __syncthreads();
        async16(Ag0 + k0, dA0);
        async16(Ag1 + k0, dA1);
        async16(Bg0 + k0, dB0);
        async16(Bg1 + k0, dB1);
        __syncthreads();
        bf16x8 af[4], bfr[4];
        #pragma unroll
        for (int i = 0; i < 4; i++)
            af[i] = *(const bf16x8*)&sA[(wy * 64 + i * 16 + m16) * BK + quad * 8];
        #pragma unroll
        for (int j = 0; j < 4; j++)
            bfr[j] = *(const bf16x8*)&sB[(wx * 64 + j * 16 + m16) * BK + quad * 8];
        #pragma unroll
        for (int i = 0; i < 4; i++)
            #pragma unroll
            for (int j = 0; j < 4; j++)
                acc[i][j] = __builtin_amdgcn_mfma_f32_16x16x32_bf16(af[i], bfr[j], acc[i][j], 0, 0, 0);
    }
    #pragma unroll
    for (int i = 0; i < 4; i++)
        #pragma unroll
        for (int j = 0; j < 4; j++)
            #pragma unroll
            for (int r = 0; r < 4; r++) {
                int rl = wy * 64 + i * 16 + quad * 4 + r;
                if (r0 + rl < cnt_e) {
                    int p = sp[rl];
                    size_t col = colBase + wx * 64 + j * 16 + m16;
                    float x = acc[i][j][r] + b_up[(size_t)ex * NI + col];
                    U[(size_t)p * NI + col] = f2bf(x / (1.0f + __expf(-x)));
                }
            }
}

// ---------------- MoE down: gather-A bf16 MFMA GEMM, atomicAdd into h ----------------
__global__ __launch_bounds__(256, 2)
void moe_down_mfma(const ushort_t* __restrict__ U, const int* __restrict__ plist,
                   const int* __restrict__ cnt, const int* __restrict__ te,
                   const int* __restrict__ to, const int* __restrict__ nt,
                   const ushort_t* __restrict__ wdnt, const float* __restrict__ b_down,
                   float* __restrict__ hout) {
    const int t = blockIdx.y;
    if (t >= *nt) return;
    const int ex = te[t], r0 = to[t], cnt_e = cnt[ex];
    __shared__ int sp[BM];
    __shared__ ushort_t sA[BM * BK], sB[BN * BK];
    const int tid = threadIdx.x;
    if (tid < BM) {
        int idx = r0 + tid;
        sp[tid] = (idx < cnt_e) ? plist[ex * SEQ + idx] : 0;
    }
    __syncthreads();
    const int wave = tid >> 6, lane = tid & 63;
    const int wy = wave >> 1, wx = wave & 1;
    const int quad = lane >> 4, m16 = lane & 15;
    const int srow = wave * 32 + (lane >> 2);
    const int scol = (lane & 3) * 8;
    const int p0 = sp[srow], p1 = sp[srow + 16];
    const ushort_t* Ag0 = U + (size_t)p0 * NI + scol;
    const ushort_t* Ag1 = U + (size_t)p1 * NI + scol;
    const size_t colBase = (size_t)blockIdx.x * BN;
    const ushort_t* Bt = wdnt + (size_t)ex * NI * HDIM;
    const ushort_t* Bg0 = Bt + (colBase + srow) * NI + scol;
    const ushort_t* Bg1 = Bg0 + (size_t)16 * NI;
    ushort_t* dA0 = &sA[(wave * 32) * BK];
    ushort_t* dA1 = &sA[(wave * 32 + 16) * BK];
    ushort_t* dB0 = &sB[(wave * 32) * BK];
    ushort_t* dB1 = &sB[(wave * 32 + 16) * BK];
    f32x4 acc[4][4] = {};
    for (int k0 = 0; k0 < NI; k0 += BK) {
        __syncthreads();
        async16(Ag0 + k0, dA0);
        async16(Ag1 + k0, dA1);
        async16(Bg0 + k0, dB0);
        async16(Bg1 + k0, dB1);
        __syncthreads();
        bf16x8 af[4], bfr[4];
        #pragma unroll
        for (int i = 0; i < 4; i++)
            af[i] = *(const bf16x8*)&sA[(wy * 64 + i * 16 + m16) * BK + quad * 8];
        #pragma unroll
        for (int j = 0; j < 4; j++)
            bfr[j] = *(const bf16x8*)&sB[(wx * 64 + j * 16 + m16) * BK + quad * 8];
        #pragma unroll
        for (int i = 0; i < 4; i++)
            #pragma unroll
            for (int j = 0; j < 4; j++)
                acc[i][j] = __builtin_amdgcn_mfma_f32_16x16x32_bf16(af[i], bfr[j], acc[i][j], 0, 0, 0);
    }
    #pragma unroll
    for (int i = 0; i < 4; i++)
        #pragma unroll
        for (int j = 0; j < 4; j++)
            #pragma unroll
            for (int r = 0; r < 4; r++) {
                int rl = wy * 64 + i * 16 + quad * 4 + r;
                if (r0 + rl < cnt_e) {
                    int tok = sp[rl] >> 1;
                    size_t col = colBase + wx * 64 + j * 16 + m16;
                    float v = acc[i][j][r] + b_down[(size_t)ex * HDIM + col];
                    atomicAdd(&hout[(size_t)tok * HDIM + col], v);
                }
            }
}

extern "C" void kernel_launch(void* const* d_in, const int* in_sizes, int n_in,
                              void* d_out, int out_size, void* d_ws, size_t ws_size,
                              hipStream_t stream) {
    (void)in_sizes; (void)n_in; (void)out_size; (void)ws_size;
    const float* hidden   = (const float*)d_in[0];
    const float* wq       = (const float*)d_in[1];
    const float* wk       = (const float*)d_in[2];
    const float* wv       = (const float*)d_in[3];
    const float* wo       = (const float*)d_in[4];
    const float* q_scale  = (const float*)d_in[5];
    const float* k_scale  = (const float*)d_in[6];
    const float* router_w = (const float*)d_in[7];
    const float* w_up     = (const float*)d_in[8];
    const float* b_up     = (const float*)d_in[9];
    const float* w_down   = (const float*)d_in[10];
    const float* b_down   = (const float*)d_in[11];

    float* out = (float*)d_out;
    float* h_out      = out;
    float* logits_out = out + (size_t)SEQ * HDIM;

    // ---- workspace layout (ushort units) ----
    // phase-1 pool (dead after out-proj):
    //   hid_hi/lo (2×4.19M), wqkv_hi/lo (2×6.29M), qkv fp32 (6.29M f = 12.58M us),
    //   attn_hi/lo (2×4.19M), wo_hi/lo (2×4.19M)     = 50.33M us
    // phase-2 pool (overlays phase-1):
    //   w_up_t (25.17M), w_down_t (25.17M), U (3.15M) = 53.48M us
    ushort_t* pool = (ushort_t*)d_ws;
    ushort_t* hid_hi  = pool;
    ushort_t* hid_lo  = hid_hi + (size_t)4194304;
    ushort_t* wqkv_hi = hid_lo + (size_t)4194304;
    ushort_t* wqkv_lo = wqkv_hi + (size_t)6291456;
    float*    qkv     = (float*)(wqkv_lo + (size_t)6291456);
    ushort_t* attn_hi = (ushort_t*)(qkv + (size_t)6291456);
    ushort_t* attn_lo = attn_hi + (size_t)4194304;
    ushort_t* wo_hi   = attn_lo + (size_t)4194304;
    ushort_t* wo_lo   = wo_hi + (size_t)4194304;

    ushort_t* w_up_t  = pool;                               // phase 2 overlay
    ushort_t* w_dn_t  = w_up_t + (size_t)25165824;
    ushort_t* U_ws    = w_dn_t + (size_t)25165824;          // ends at 53.48M us

    ushort_t* hbf     = pool + (size_t)53477376;            // after max(pool phases)
    int* cnt_ws   = (int*)(hbf + (size_t)4194304);
    int* plist_ws = cnt_ws + 16;
    int* te_ws    = plist_ws + NE * SEQ;
    int* to_ws    = te_ws + 64;
    int* nt_ws    = to_ws + 64;

    // 1. split hidden -> bf16 hi/lo
    split_cvt<<<dim3(4096), 256, 0, stream>>>(hidden, hid_hi, hid_lo);
    // 2. transpose+split weights for pre-router GEMMs
    transpose_split<<<dim3(64, 64), 256, 0, stream>>>(wq, wqkv_hi, wqkv_lo, HDIM, 2048);
    transpose_split<<<dim3(16, 64), 256, 0, stream>>>(wk, wqkv_hi + (size_t)2048 * HDIM,
                                                      wqkv_lo + (size_t)2048 * HDIM, HDIM, 512);
    transpose_split<<<dim3(16, 64), 256, 0, stream>>>(wv, wqkv_hi + (size_t)2560 * HDIM,
                                                      wqkv_lo + (size_t)2560 * HDIM, HDIM, 512);
    transpose_split<<<dim3(64, 64), 256, 0, stream>>>(wo, wo_hi, wo_lo, HDIM, HDIM);

    // 3. fused QKV projection (split-bf16 MFMA, ~fp32 precision)
    gemm_split<<<dim3(QKVS / BN, SEQ / BM), 256, 0, stream>>>(
        hid_hi, hid_lo, wqkv_hi, wqkv_lo, qkv, QKVS, nullptr, nullptr, QKVS, HDIM);

    // 4. RMSNorm + RoPE in place on qkv
    norm_rope<<<dim3(SEQ, NHQ + NHKV), 128, 0, stream>>>(qkv, q_scale, k_scale);

    // 5. flash attention -> split-bf16 attn output
    attn_flash<<<dim3(SEQ / QT, NHQ), 256, 0, stream>>>(qkv, attn_hi, attn_lo);

    // 6. out-proj + residual -> h fp32 (d_out) + bf16 mirror hbf
    gemm_split<<<dim3(HDIM / BN, SEQ / BM), 256, 0, stream>>>(
        attn_hi, attn_lo, wo_hi, wo_lo, h_out, HDIM, hidden, hbf, HDIM, HDIM);

    // 7. MoE weight transposes (after out-proj: they overlay phase-1 buffers)
    transpose_cvt<<<dim3(24, 64, 16), 256, 0, stream>>>(w_up, w_up_t, HDIM, NI);
    transpose_cvt<<<dim3(64, 24, 16), 256, 0, stream>>>(w_down, w_dn_t, NI, HDIM);

    // 8. router + grouping
    hipMemsetAsync(cnt_ws, 0, NE * sizeof(int), stream);
    router_topk<<<dim3(SEQ), 256, 0, stream>>>(h_out, router_w, logits_out, cnt_ws, plist_ws);
    tilemap<<<1, 64, 0, stream>>>(cnt_ws, te_ws, to_ws, nt_ws);

    // 9. expert-grouped MoE (bf16 MFMA), down-proj atomically accumulates into h
    moe_up_mfma<<<dim3(NI / BN, MOE_TILES), 256, 0, stream>>>(
        hbf, plist_ws, cnt_ws, te_ws, to_ws, nt_ws, w_up_t, b_up, U_ws);
    moe_down_mfma<<<dim3(HDIM / BN, MOE_TILES), 256, 0, stream>>>(
        U_ws, plist_ws, cnt_ws, te_ws, to_ws, nt_ws, w_dn_t, b_down, h_out);
}